// Round 5
// baseline (354.225 us; speedup 1.0000x reference)
//
#include <hip/hip_runtime.h>
#include <hip/hip_bf16.h>
#include <math.h>

#define T_TOK   1024
#define D_MODEL 1024
#define H_HEADS 8
#define DKEY    128
#define NKEYS   256
#define TOPK    16
#define TPB     4

__device__ __forceinline__ float dot4(float4 a, float4 b){
  return a.x*b.x + a.y*b.y + a.z*b.z + a.w*b.w;
}

// ---------------- K1: RMSNorm ----------------
__global__ __launch_bounds__(256) void k_rmsnorm(const float* __restrict__ x,
                                                 const float* __restrict__ nw,
                                                 float* __restrict__ xn)
{
  const int t = blockIdx.x, tid = threadIdx.x;
  const float4 v = *(const float4*)(x + (size_t)t*D_MODEL + tid*4);
  float ss = dot4(v, v);
  #pragma unroll
  for (int m = 1; m < 64; m <<= 1) ss += __shfl_xor(ss, m, 64);
  __shared__ float part[4];
  const int lane = tid & 63, wid = tid >> 6;
  if (lane == 0) part[wid] = ss;
  __syncthreads();
  const float tot = part[0] + part[1] + part[2] + part[3];
  const float inv = rsqrtf(tot * (1.0f/(float)D_MODEL) + 1e-5f);
  const float4 w = *(const float4*)(nw + tid*4);
  float4 o;
  o.x = v.x*inv*w.x; o.y = v.y*inv*w.y; o.z = v.z*inv*w.z; o.w = v.w*inv*w.w;
  *(float4*)(xn + (size_t)t*D_MODEL + tid*4) = o;
}

// ---------------- K2: fp32 GEMM q = xn @ wq, 64x128 tile, 4x8 micro ----------
#define QBM 64
#define QBN 128
#define QBK 16
__global__ __launch_bounds__(256) void k_qgemm(const float* __restrict__ A,
                                               const float* __restrict__ B,
                                               float* __restrict__ C)
{
  const int N = 2048, Kd = 1024;
  __shared__ float As[QBK][QBM+4];   // [k][m]
  __shared__ float Bs[QBK][QBN+4];   // [k][n]
  const int tid = threadIdx.x;
  const int row0 = blockIdx.y * QBM, col0 = blockIdx.x * QBN;
  const int alr = tid >> 2,  alk = (tid & 3) * 4;   // A: row, k-offset
  const int blk = tid >> 4,  blc = (tid & 15) * 8;  // B: k-row, col-offset
  const int ty = tid >> 4,   tx = tid & 15;         // micro-tile: 4 rows x 8 cols
  float acc[4][8] = {{0}};
  for (int k0 = 0; k0 < Kd; k0 += QBK){
    const float4 a  = *(const float4*)(A + (size_t)(row0+alr)*Kd + k0 + alk);
    const float4 b0 = *(const float4*)(B + (size_t)(k0+blk)*N + col0 + blc);
    const float4 b1 = *(const float4*)(B + (size_t)(k0+blk)*N + col0 + blc + 4);
    As[alk+0][alr]=a.x; As[alk+1][alr]=a.y; As[alk+2][alr]=a.z; As[alk+3][alr]=a.w;
    *(float4*)&Bs[blk][blc]   = b0;
    *(float4*)&Bs[blk][blc+4] = b1;
    __syncthreads();
    #pragma unroll
    for (int kk = 0; kk < QBK; kk++){
      const float4 av  = *(const float4*)&As[kk][ty*4];
      const float4 bv0 = *(const float4*)&Bs[kk][tx*8];
      const float4 bv1 = *(const float4*)&Bs[kk][tx*8+4];
      const float af[4] = {av.x, av.y, av.z, av.w};
      const float bf[8] = {bv0.x, bv0.y, bv0.z, bv0.w, bv1.x, bv1.y, bv1.z, bv1.w};
      #pragma unroll
      for (int i = 0; i < 4; i++)
        #pragma unroll
        for (int j = 0; j < 8; j++)
          acc[i][j] += af[i] * bf[j];
    }
    __syncthreads();
  }
  #pragma unroll
  for (int i = 0; i < 4; i++){
    float4 o0, o1;
    o0.x=acc[i][0]; o0.y=acc[i][1]; o0.z=acc[i][2]; o0.w=acc[i][3];
    o1.x=acc[i][4]; o1.y=acc[i][5]; o1.z=acc[i][6]; o1.w=acc[i][7];
    float* crow = C + (size_t)(row0 + ty*4 + i)*N + col0 + tx*8;
    *(float4*)crow = o0;
    *(float4*)(crow+4) = o1;
  }
}

// ---------------- K3a: sims GEMM ----------------
#define TBK 16
__global__ __launch_bounds__(256) void k_simgemm(const float* __restrict__ Q,
                                                 const float* __restrict__ keys,
                                                 float* __restrict__ sims)
{
  const int hp = blockIdx.z;
  const int t0 = blockIdx.y * 64, kb0 = blockIdx.x * 64;
  const float* A = Q + (size_t)t0*2048 + (hp>>1)*256 + (hp&1)*128;
  const float* B = keys + ((size_t)((hp>>1)*NKEYS + kb0)*2 + (hp&1)) * DKEY;
  __shared__ float As[TBK][64+4];
  __shared__ float Bs[TBK][64+4];
  const int tid = threadIdx.x;
  const int ar = tid >> 2, ac = (tid & 3) * 4;
  const int ty = tid >> 4, tx = tid & 15;
  float acc[4][4] = {{0}};
  for (int kd = 0; kd < DKEY; kd += TBK){
    const float4 a = *(const float4*)(A + (size_t)ar*2048 + kd + ac);
    const float4 b = *(const float4*)(B + (size_t)ar*256  + kd + ac);
    As[ac+0][ar] = a.x; As[ac+1][ar] = a.y; As[ac+2][ar] = a.z; As[ac+3][ar] = a.w;
    Bs[ac+0][ar] = b.x; Bs[ac+1][ar] = b.y; Bs[ac+2][ar] = b.z; Bs[ac+3][ar] = b.w;
    __syncthreads();
    #pragma unroll
    for (int kk = 0; kk < TBK; kk++){
      const float4 av = *(const float4*)&As[kk][ty*4];
      const float4 bv = *(const float4*)&Bs[kk][tx*4];
      acc[0][0] += av.x*bv.x; acc[0][1] += av.x*bv.y; acc[0][2] += av.x*bv.z; acc[0][3] += av.x*bv.w;
      acc[1][0] += av.y*bv.x; acc[1][1] += av.y*bv.y; acc[1][2] += av.y*bv.z; acc[1][3] += av.y*bv.w;
      acc[2][0] += av.z*bv.x; acc[2][1] += av.z*bv.y; acc[2][2] += av.z*bv.z; acc[2][3] += av.z*bv.w;
      acc[3][0] += av.w*bv.x; acc[3][1] += av.w*bv.y; acc[3][2] += av.w*bv.z; acc[3][3] += av.w*bv.w;
    }
    __syncthreads();
  }
  float* Cb = sims + (size_t)t0*4096 + hp*256 + kb0;
  #pragma unroll
  for (int i = 0; i < 4; i++){
    float4 o; o.x = acc[i][0]; o.y = acc[i][1]; o.z = acc[i][2]; o.w = acc[i][3];
    *(float4*)(Cb + (size_t)(ty*4 + i)*4096 + tx*4) = o;
  }
}

// ---------------- K3b: two-stage top-k ----------------
__device__ __forceinline__ void wave_top16(float v[4], int lane, float* tvO, int* tiO)
{
  for (int r = 0; r < 16; r++){
    float bv = v[0]; int bj = 0;
    #pragma unroll
    for (int j = 1; j < 4; j++) if (v[j] > bv){ bv = v[j]; bj = j; }
    int bi = lane*4 + bj;
    #pragma unroll
    for (int m = 1; m < 64; m <<= 1){
      const float ov = __shfl_xor(bv, m, 64);
      const int   oi = __shfl_xor(bi, m, 64);
      if (ov > bv || (ov == bv && oi < bi)){ bv = ov; bi = oi; }
    }
    if (lane == 0){ tvO[r] = bv; tiO[r] = bi; }
    if ((bi >> 2) == lane) v[bi & 3] = -INFINITY;
  }
}

__global__ __launch_bounds__(256) void k_topk(const float* __restrict__ sims,
                                              int* __restrict__ fidxO,
                                              float* __restrict__ gateO)
{
  const int h  = blockIdx.x;
  const int t0 = blockIdx.y * TPB;
  const int tid = threadIdx.x;
  const int w = tid >> 6, lane = tid & 63;
  const int t = t0 + w;
  __shared__ float tv[TPB][2][TOPK];
  __shared__ int   ti[TPB][2][TOPK];

  float v0[4], v1[4];
  {
    const float4 a = *(const float4*)(sims + (size_t)t*4096 + (h*2+0)*256 + lane*4);
    const float4 b = *(const float4*)(sims + (size_t)t*4096 + (h*2+1)*256 + lane*4);
    v0[0]=a.x; v0[1]=a.y; v0[2]=a.z; v0[3]=a.w;
    v1[0]=b.x; v1[1]=b.y; v1[2]=b.z; v1[3]=b.w;
  }
  wave_top16(v0, lane, &tv[w][0][0], &ti[w][0][0]);
  wave_top16(v1, lane, &tv[w][1][0], &ti[w][1][0]);

  float cv[4];
  const int i0 = lane >> 2;
  #pragma unroll
  for (int j = 0; j < 4; j++)
    cv[j] = tv[w][0][i0] + tv[w][1][4*(lane & 3) + j];

  const size_t obase = (size_t)((t)*H_HEADS + h) * TOPK;
  for (int r = 0; r < 16; r++){
    float bv = cv[0]; int bj = 0;
    #pragma unroll
    for (int j = 1; j < 4; j++) if (cv[j] > bv){ bv = cv[j]; bj = j; }
    int bc = lane*4 + bj;
    #pragma unroll
    for (int m = 1; m < 64; m <<= 1){
      const float ov = __shfl_xor(bv, m, 64);
      const int   oc = __shfl_xor(bc, m, 64);
      if (ov > bv || (ov == bv && oc < bc)){ bv = ov; bc = oc; }
    }
    if (lane == 0){
      fidxO[obase + r] = ti[w][0][bc >> 4] * NKEYS + ti[w][1][bc & 15];
      gateO[obase + r] = bv > 0.0f ? bv : 0.0f;
    }
    if ((bc >> 2) == lane) cv[bc & 3] = -INFINITY;
  }
}

// ---------------- K4a: down-projection + GELU*gate -> coeff ----------------
__global__ __launch_bounds__(256) void k_peer_down(const float* __restrict__ xn,
                                                   const float* __restrict__ ed,
                                                   const int* __restrict__ fidx,
                                                   const float* __restrict__ gate,
                                                   float* __restrict__ coeff)
{
  const int b = blockIdx.x;           // t*8 + h
  const int t = b >> 3;
  const int tid = threadIdx.x, w = tid >> 6, lane = tid & 63;
  const int base = b * TOPK;

  float4 xv[4];
  #pragma unroll
  for (int j = 0; j < 4; j++)
    xv[j] = *(const float4*)(xn + (size_t)t*D_MODEL + j*256 + lane*4);

  int e[4];
  #pragma unroll
  for (int r = 0; r < 4; r++) e[r] = fidx[base + w*4 + r];

  float4 wv[4][4];
  #pragma unroll
  for (int r = 0; r < 4; r++)
    #pragma unroll
    for (int j = 0; j < 4; j++)
      wv[r][j] = *(const float4*)(ed + (size_t)e[r]*D_MODEL + j*256 + lane*4);

  float s[4];
  #pragma unroll
  for (int r = 0; r < 4; r++){
    float p = dot4(wv[r][0], xv[0]) + dot4(wv[r][1], xv[1])
            + dot4(wv[r][2], xv[2]) + dot4(wv[r][3], xv[3]);
    #pragma unroll
    for (int m = 1; m < 64; m <<= 1) p += __shfl_xor(p, m, 64);
    s[r] = p;
  }
  if (lane < 4){
    const float hs = (lane == 0) ? s[0] : (lane == 1) ? s[1] : (lane == 2) ? s[2] : s[3];
    const float g = 0.5f * hs * (1.0f + erff(hs * 0.70710678118654752440f));
    coeff[base + w*4 + lane] = g * gate[base + w*4 + lane];
  }
}

// ---------------- K4b: up-projection gather, 2 blocks/token x 128 thr ----------
__global__ __launch_bounds__(128) void k_peer_up(const float* __restrict__ eu,
                                                 const int* __restrict__ fidx,
                                                 const float* __restrict__ coeff,
                                                 float* __restrict__ out)
{
  const int b = blockIdx.x, t = b >> 1, half = b & 1;
  const int tid = threadIdx.x;
  __shared__ int   sidx[H_HEADS*TOPK];
  __shared__ float sc[H_HEADS*TOPK];
  sidx[tid] = fidx[(size_t)t*H_HEADS*TOPK + tid];
  sc[tid]   = coeff[(size_t)t*H_HEADS*TOPK + tid];
  __syncthreads();
  const int col = half*512 + tid*4;
  float4 acc = {0.f, 0.f, 0.f, 0.f};
  for (int j = 0; j < H_HEADS*TOPK; j += 8){
    float4 wv[8];
    #pragma unroll
    for (int u = 0; u < 8; u++)
      wv[u] = *(const float4*)(eu + (size_t)sidx[j+u]*D_MODEL + col);
    #pragma unroll
    for (int u = 0; u < 8; u++){
      const float c = sc[j+u];
      acc.x += c*wv[u].x; acc.y += c*wv[u].y; acc.z += c*wv[u].z; acc.w += c*wv[u].w;
    }
  }
  *(float4*)(out + (size_t)t*D_MODEL + col) = acc;
}

// ---------------- launch ----------------
extern "C" void kernel_launch(void* const* d_in, const int* in_sizes, int n_in,
                              void* d_out, int out_size, void* d_ws, size_t ws_size,
                              hipStream_t stream)
{
  const float* x      = (const float*)d_in[0];
  const float* norm_w = (const float*)d_in[1];
  const float* wq     = (const float*)d_in[2];
  const float* keys   = (const float*)d_in[3];
  const float* ed     = (const float*)d_in[4];
  const float* eu     = (const float*)d_in[5];
  float* out = (float*)d_out;

  float* xn   = (float*)d_ws;                            // 1024*1024 f32
  float* q    = xn + (size_t)T_TOK * D_MODEL;            // 1024*2048 f32
  int*   fidx = (int*)(q + (size_t)T_TOK * 2048);        // 1024*8*16 i32
  float* gate = (float*)(fidx + (size_t)T_TOK * H_HEADS * TOPK);
  float* sims = gate + (size_t)T_TOK * H_HEADS * TOPK;   // 1024*4096 f32 (16MB)
  float* coeff = sims;  // alias: sims dead after k_topk (stream-ordered)

  k_rmsnorm<<<T_TOK, 256, 0, stream>>>(x, norm_w, xn);
  k_qgemm<<<dim3(2048/QBN, 1024/QBM), 256, 0, stream>>>(xn, wq, q);
  k_simgemm<<<dim3(NKEYS/64, T_TOK/64, 16), 256, 0, stream>>>(q, keys, sims);
  k_topk<<<dim3(H_HEADS, T_TOK/TPB), 256, 0, stream>>>(sims, fidx, gate);
  k_peer_down<<<T_TOK*H_HEADS, 256, 0, stream>>>(xn, ed, fidx, gate, coeff);
  k_peer_up<<<T_TOK*2, 128, 0, stream>>>(eu, fidx, coeff, out);
}

// Round 6
// 311.754 us; speedup vs baseline: 1.1362x; 1.1362x over previous
//
#include <hip/hip_runtime.h>
#include <hip/hip_bf16.h>
#include <math.h>

#define T_TOK   1024
#define D_MODEL 1024
#define H_HEADS 8
#define DKEY    128
#define NKEYS   256
#define TOPK    16
#define TPB     4

__device__ __forceinline__ float dot4(float4 a, float4 b){
  return a.x*b.x + a.y*b.y + a.z*b.z + a.w*b.w;
}

// ---------------- K1: RMSNorm ----------------
__global__ __launch_bounds__(256) void k_rmsnorm(const float* __restrict__ x,
                                                 const float* __restrict__ nw,
                                                 float* __restrict__ xn)
{
  const int t = blockIdx.x, tid = threadIdx.x;
  const float4 v = *(const float4*)(x + (size_t)t*D_MODEL + tid*4);
  float ss = dot4(v, v);
  #pragma unroll
  for (int m = 1; m < 64; m <<= 1) ss += __shfl_xor(ss, m, 64);
  __shared__ float part[4];
  const int lane = tid & 63, wid = tid >> 6;
  if (lane == 0) part[wid] = ss;
  __syncthreads();
  const float tot = part[0] + part[1] + part[2] + part[3];
  const float inv = rsqrtf(tot * (1.0f/(float)D_MODEL) + 1e-5f);
  const float4 w = *(const float4*)(nw + tid*4);
  float4 o;
  o.x = v.x*inv*w.x; o.y = v.y*inv*w.y; o.z = v.z*inv*w.z; o.w = v.w*inv*w.w;
  *(float4*)(xn + (size_t)t*D_MODEL + tid*4) = o;
}

// ---------------- K2: fp32 GEMM q = xn @ wq, 64x64 tile, 4x4 micro, TBK=32 ----
// 512 blocks (2/CU), conflict-free LDS (R3-proven layout), halved barrier count.
#define GBM 64
#define GBK 32
__global__ __launch_bounds__(256) void k_qgemm(const float* __restrict__ A,
                                               const float* __restrict__ B,
                                               float* __restrict__ C)
{
  const int N = 2048, Kd = 1024;
  __shared__ float As[GBK][GBM+4];
  __shared__ float Bs[GBK][GBM+4];
  const int tid = threadIdx.x;
  const int row0 = blockIdx.y * GBM, col0 = blockIdx.x * GBM;
  const int ar = tid >> 2,  ak = (tid & 3) * 4;   // A: row ar, k ak(+16)
  const int br = tid >> 4,  bc = (tid & 15) * 4;  // B: k br(+16), col bc
  const int ty = tid >> 4,  tx = tid & 15;
  float acc[4][4] = {{0}};
  for (int k0 = 0; k0 < Kd; k0 += GBK){
    const float4 a0 = *(const float4*)(A + (size_t)(row0+ar)*Kd + k0 + ak);
    const float4 a1 = *(const float4*)(A + (size_t)(row0+ar)*Kd + k0 + ak + 16);
    const float4 b0 = *(const float4*)(B + (size_t)(k0+br)*N + col0 + bc);
    const float4 b1 = *(const float4*)(B + (size_t)(k0+br+16)*N + col0 + bc);
    As[ak+0][ar]=a0.x; As[ak+1][ar]=a0.y; As[ak+2][ar]=a0.z; As[ak+3][ar]=a0.w;
    As[ak+16][ar]=a1.x; As[ak+17][ar]=a1.y; As[ak+18][ar]=a1.z; As[ak+19][ar]=a1.w;
    *(float4*)&Bs[br][bc]    = b0;
    *(float4*)&Bs[br+16][bc] = b1;
    __syncthreads();
    #pragma unroll
    for (int kk = 0; kk < GBK; kk++){
      const float4 av = *(const float4*)&As[kk][ty*4];
      const float4 bv = *(const float4*)&Bs[kk][tx*4];
      acc[0][0] += av.x*bv.x; acc[0][1] += av.x*bv.y; acc[0][2] += av.x*bv.z; acc[0][3] += av.x*bv.w;
      acc[1][0] += av.y*bv.x; acc[1][1] += av.y*bv.y; acc[1][2] += av.y*bv.z; acc[1][3] += av.y*bv.w;
      acc[2][0] += av.z*bv.x; acc[2][1] += av.z*bv.y; acc[2][2] += av.z*bv.z; acc[2][3] += av.z*bv.w;
      acc[3][0] += av.w*bv.x; acc[3][1] += av.w*bv.y; acc[3][2] += av.w*bv.z; acc[3][3] += av.w*bv.w;
    }
    __syncthreads();
  }
  #pragma unroll
  for (int i = 0; i < 4; i++){
    float4 o; o.x = acc[i][0]; o.y = acc[i][1]; o.z = acc[i][2]; o.w = acc[i][3];
    *(float4*)(C + (size_t)(row0 + ty*4 + i)*N + col0 + tx*4) = o;
  }
}

// ---------------- K3a: sims GEMM ----------------
#define TBK 16
__global__ __launch_bounds__(256) void k_simgemm(const float* __restrict__ Q,
                                                 const float* __restrict__ keys,
                                                 float* __restrict__ sims)
{
  const int hp = blockIdx.z;
  const int t0 = blockIdx.y * 64, kb0 = blockIdx.x * 64;
  const float* A = Q + (size_t)t0*2048 + (hp>>1)*256 + (hp&1)*128;
  const float* B = keys + ((size_t)((hp>>1)*NKEYS + kb0)*2 + (hp&1)) * DKEY;
  __shared__ float As[TBK][64+4];
  __shared__ float Bs[TBK][64+4];
  const int tid = threadIdx.x;
  const int ar = tid >> 2, ac = (tid & 3) * 4;
  const int ty = tid >> 4, tx = tid & 15;
  float acc[4][4] = {{0}};
  for (int kd = 0; kd < DKEY; kd += TBK){
    const float4 a = *(const float4*)(A + (size_t)ar*2048 + kd + ac);
    const float4 b = *(const float4*)(B + (size_t)ar*256  + kd + ac);
    As[ac+0][ar] = a.x; As[ac+1][ar] = a.y; As[ac+2][ar] = a.z; As[ac+3][ar] = a.w;
    Bs[ac+0][ar] = b.x; Bs[ac+1][ar] = b.y; Bs[ac+2][ar] = b.z; Bs[ac+3][ar] = b.w;
    __syncthreads();
    #pragma unroll
    for (int kk = 0; kk < TBK; kk++){
      const float4 av = *(const float4*)&As[kk][ty*4];
      const float4 bv = *(const float4*)&Bs[kk][tx*4];
      acc[0][0] += av.x*bv.x; acc[0][1] += av.x*bv.y; acc[0][2] += av.x*bv.z; acc[0][3] += av.x*bv.w;
      acc[1][0] += av.y*bv.x; acc[1][1] += av.y*bv.y; acc[1][2] += av.y*bv.z; acc[1][3] += av.y*bv.w;
      acc[2][0] += av.z*bv.x; acc[2][1] += av.z*bv.y; acc[2][2] += av.z*bv.z; acc[2][3] += av.z*bv.w;
      acc[3][0] += av.w*bv.x; acc[3][1] += av.w*bv.y; acc[3][2] += av.w*bv.z; acc[3][3] += av.w*bv.w;
    }
    __syncthreads();
  }
  float* Cb = sims + (size_t)t0*4096 + hp*256 + kb0;
  #pragma unroll
  for (int i = 0; i < 4; i++){
    float4 o; o.x = acc[i][0]; o.y = acc[i][1]; o.z = acc[i][2]; o.w = acc[i][3];
    *(float4*)(Cb + (size_t)(ty*4 + i)*4096 + tx*4) = o;
  }
}

// ---------------- K3b: two-stage top-k ----------------
__device__ __forceinline__ void wave_top16(float v[4], int lane, float* tvO, int* tiO)
{
  for (int r = 0; r < 16; r++){
    float bv = v[0]; int bj = 0;
    #pragma unroll
    for (int j = 1; j < 4; j++) if (v[j] > bv){ bv = v[j]; bj = j; }
    int bi = lane*4 + bj;
    #pragma unroll
    for (int m = 1; m < 64; m <<= 1){
      const float ov = __shfl_xor(bv, m, 64);
      const int   oi = __shfl_xor(bi, m, 64);
      if (ov > bv || (ov == bv && oi < bi)){ bv = ov; bi = oi; }
    }
    if (lane == 0){ tvO[r] = bv; tiO[r] = bi; }
    if ((bi >> 2) == lane) v[bi & 3] = -INFINITY;
  }
}

__global__ __launch_bounds__(256) void k_topk(const float* __restrict__ sims,
                                              int* __restrict__ fidxO,
                                              float* __restrict__ gateO)
{
  const int h  = blockIdx.x;
  const int t0 = blockIdx.y * TPB;
  const int tid = threadIdx.x;
  const int w = tid >> 6, lane = tid & 63;
  const int t = t0 + w;
  __shared__ float tv[TPB][2][TOPK];
  __shared__ int   ti[TPB][2][TOPK];

  float v0[4], v1[4];
  {
    const float4 a = *(const float4*)(sims + (size_t)t*4096 + (h*2+0)*256 + lane*4);
    const float4 b = *(const float4*)(sims + (size_t)t*4096 + (h*2+1)*256 + lane*4);
    v0[0]=a.x; v0[1]=a.y; v0[2]=a.z; v0[3]=a.w;
    v1[0]=b.x; v1[1]=b.y; v1[2]=b.z; v1[3]=b.w;
  }
  wave_top16(v0, lane, &tv[w][0][0], &ti[w][0][0]);
  wave_top16(v1, lane, &tv[w][1][0], &ti[w][1][0]);

  float cv[4];
  const int i0 = lane >> 2;
  #pragma unroll
  for (int j = 0; j < 4; j++)
    cv[j] = tv[w][0][i0] + tv[w][1][4*(lane & 3) + j];

  const size_t obase = (size_t)((t)*H_HEADS + h) * TOPK;
  for (int r = 0; r < 16; r++){
    float bv = cv[0]; int bj = 0;
    #pragma unroll
    for (int j = 1; j < 4; j++) if (cv[j] > bv){ bv = cv[j]; bj = j; }
    int bc = lane*4 + bj;
    #pragma unroll
    for (int m = 1; m < 64; m <<= 1){
      const float ov = __shfl_xor(bv, m, 64);
      const int   oc = __shfl_xor(bc, m, 64);
      if (ov > bv || (ov == bv && oc < bc)){ bv = ov; bc = oc; }
    }
    if (lane == 0){
      fidxO[obase + r] = ti[w][0][bc >> 4] * NKEYS + ti[w][1][bc & 15];
      gateO[obase + r] = bv > 0.0f ? bv : 0.0f;
    }
    if ((bc >> 2) == lane) cv[bc & 3] = -INFINITY;
  }
}

// ---------------- K4a: down-projection + GELU*gate -> coeff ----------------
__global__ __launch_bounds__(256) void k_peer_down(const float* __restrict__ xn,
                                                   const float* __restrict__ ed,
                                                   const int* __restrict__ fidx,
                                                   const float* __restrict__ gate,
                                                   float* __restrict__ coeff)
{
  const int b = blockIdx.x;           // t*8 + h
  const int t = b >> 3;
  const int tid = threadIdx.x, w = tid >> 6, lane = tid & 63;
  const int base = b * TOPK;

  float4 xv[4];
  #pragma unroll
  for (int j = 0; j < 4; j++)
    xv[j] = *(const float4*)(xn + (size_t)t*D_MODEL + j*256 + lane*4);

  int e[4];
  #pragma unroll
  for (int r = 0; r < 4; r++) e[r] = fidx[base + w*4 + r];

  float4 wv[4][4];
  #pragma unroll
  for (int r = 0; r < 4; r++)
    #pragma unroll
    for (int j = 0; j < 4; j++)
      wv[r][j] = *(const float4*)(ed + (size_t)e[r]*D_MODEL + j*256 + lane*4);

  float s[4];
  #pragma unroll
  for (int r = 0; r < 4; r++){
    float p = dot4(wv[r][0], xv[0]) + dot4(wv[r][1], xv[1])
            + dot4(wv[r][2], xv[2]) + dot4(wv[r][3], xv[3]);
    #pragma unroll
    for (int m = 1; m < 64; m <<= 1) p += __shfl_xor(p, m, 64);
    s[r] = p;
  }
  if (lane < 4){
    const float hs = (lane == 0) ? s[0] : (lane == 1) ? s[1] : (lane == 2) ? s[2] : s[3];
    const float g = 0.5f * hs * (1.0f + erff(hs * 0.70710678118654752440f));
    coeff[base + w*4 + lane] = g * gate[base + w*4 + lane];
  }
}

// ---------------- K4b: up-projection streaming gather (R3-proven 256-thr) ------
__global__ __launch_bounds__(256) void k_peer_up(const float* __restrict__ eu,
                                                 const int* __restrict__ fidx,
                                                 const float* __restrict__ coeff,
                                                 float* __restrict__ out)
{
  const int t = blockIdx.x, tid = threadIdx.x;
  __shared__ int   sidx[H_HEADS*TOPK];
  __shared__ float sc[H_HEADS*TOPK];
  if (tid < H_HEADS*TOPK){
    sidx[tid] = fidx[(size_t)t*H_HEADS*TOPK + tid];
    sc[tid]   = coeff[(size_t)t*H_HEADS*TOPK + tid];
  }
  __syncthreads();
  float4 acc = {0.f, 0.f, 0.f, 0.f};
  for (int j = 0; j < H_HEADS*TOPK; j += 8){
    float4 wv[8];
    #pragma unroll
    for (int u = 0; u < 8; u++)
      wv[u] = *(const float4*)(eu + (size_t)sidx[j+u]*D_MODEL + tid*4);
    #pragma unroll
    for (int u = 0; u < 8; u++){
      const float c = sc[j+u];
      acc.x += c*wv[u].x; acc.y += c*wv[u].y; acc.z += c*wv[u].z; acc.w += c*wv[u].w;
    }
  }
  *(float4*)(out + (size_t)t*D_MODEL + tid*4) = acc;
}

// ---------------- launch ----------------
extern "C" void kernel_launch(void* const* d_in, const int* in_sizes, int n_in,
                              void* d_out, int out_size, void* d_ws, size_t ws_size,
                              hipStream_t stream)
{
  const float* x      = (const float*)d_in[0];
  const float* norm_w = (const float*)d_in[1];
  const float* wq     = (const float*)d_in[2];
  const float* keys   = (const float*)d_in[3];
  const float* ed     = (const float*)d_in[4];
  const float* eu     = (const float*)d_in[5];
  float* out = (float*)d_out;

  float* xn   = (float*)d_ws;                            // 1024*1024 f32
  float* q    = xn + (size_t)T_TOK * D_MODEL;            // 1024*2048 f32
  int*   fidx = (int*)(q + (size_t)T_TOK * 2048);        // 1024*8*16 i32
  float* gate = (float*)(fidx + (size_t)T_TOK * H_HEADS * TOPK);
  float* sims = gate + (size_t)T_TOK * H_HEADS * TOPK;   // 1024*4096 f32 (16MB)
  float* coeff = sims;  // alias: sims dead after k_topk (stream-ordered)

  k_rmsnorm<<<T_TOK, 256, 0, stream>>>(x, norm_w, xn);
  k_qgemm<<<dim3(2048/GBM, 1024/GBM), 256, 0, stream>>>(xn, wq, q);
  k_simgemm<<<dim3(NKEYS/64, T_TOK/64, 16), 256, 0, stream>>>(q, keys, sims);
  k_topk<<<dim3(H_HEADS, T_TOK/TPB), 256, 0, stream>>>(sims, fidx, gate);
  k_peer_down<<<T_TOK*H_HEADS, 256, 0, stream>>>(xn, ed, fidx, gate, coeff);
  k_peer_up<<<T_TOK, 256, 0, stream>>>(eu, fidx, coeff, out);
}